// Round 2
// baseline (4988.227 us; speedup 1.0000x reference)
//
#include <hip/hip_runtime.h>
#include <hip/hip_bf16.h>
#include <hip/hip_cooperative_groups.h>

namespace cg = cooperative_groups;

#define TSTEPS 32
#define HDIM 1024

typedef __bf16 bf16x8 __attribute__((ext_vector_type(8)));
typedef float f32x4 __attribute__((ext_vector_type(4)));
typedef unsigned short u16;
typedef unsigned int u32;

__device__ __forceinline__ u32 f2bf(float f) {
    u32 u = __float_as_uint(f);
    return (u + 0x7FFFu + ((u >> 16) & 1u)) >> 16;   // RNE
}
__device__ __forceinline__ u32 pack2(float a, float b) {
    return f2bf(a) | (f2bf(b) << 16);
}
__device__ __forceinline__ float sigf(float x) { return 1.f / (1.f + __expf(-x)); }
__device__ __forceinline__ float tanhfast(float x) { return 1.f - 2.f / (1.f + __expf(2.f * x)); }

// Persistent cooperative kernel: 256 blocks (1/CU) x 1024 threads (16 waves).
// Block owns j-set of 16 hidden cols (x4 gates = 64 gate-cols; W slice 128KB in
// LDS, loaded once) and 512 batch rows (32 rows/wave). c lives in registers.
// h ping-pongs through global bf16 buffers; one grid.sync per step.
__global__ __launch_bounds__(1024, 4) void k_persist(
    const float* __restrict__ fd, const float* __restrict__ h0,
    const float* __restrict__ c0, const float* __restrict__ Wih,
    const float* __restrict__ Whh, const float* __restrict__ bih,
    const float* __restrict__ bhh, const float* __restrict__ fcw,
    const float* __restrict__ fcb, u16* hb0, u16* hb1, float* out)
{
    __shared__ uint4 wlds[64][128];   // [gate-col][k-unit ^ (bc&7)], 128 KB
    cg::grid_group grid = cg::this_grid();

    const int tid  = threadIdx.x;
    const int lane = tid & 63, wave = tid >> 6;
    const int lr = lane & 15, lk = lane >> 4;
    const int blk = blockIdx.x;
    const int cgp = blk & 63, rgp = blk >> 6;
    const int jb = cgp * 16;
    const int rowbase = rgp * 512 + wave * 32;
    const int j = jb + lr;

    // ---- one-time: stage W slice (f32 -> bf16, swizzled) ----
#pragma unroll
    for (int u = 0; u < 8; ++u) {
        int idx = u * 1024 + tid;            // 64 rows x 128 16B-units
        int bc = idx >> 7, ku = idx & 127;
        int g = bc >> 4, jl = bc & 15;
        const float4* src = (const float4*)(Whh + (size_t)(g * HDIM + jb + jl) * HDIM + ku * 8);
        float4 lo = src[0], hi = src[1];
        uint4 pk = { pack2(lo.x, lo.y), pack2(lo.z, lo.w), pack2(hi.x, hi.y), pack2(hi.z, hi.w) };
        wlds[bc][ku ^ (bc & 7)] = pk;
    }
    // ---- one-time: h0 -> bf16 (each block converts a 8192-elem slice) ----
    {
        int ib = blk * 8192 + tid * 8;
        const float4* src = (const float4*)(h0 + ib);
        float4 lo = src[0], hi = src[1];
        uint4 pk = { pack2(lo.x, lo.y), pack2(lo.z, lo.w), pack2(hi.x, hi.y), pack2(hi.z, hi.w) };
        *(uint4*)(hb0 + ib) = pk;
    }
    // ---- one-time: init out = fc_b ----
    if (cgp == 0) {
        float fb = fcb[0];
        for (int i = tid; i < 512 * TSTEPS; i += 1024)
            out[rgp * 512 * TSTEPS + i] = fb;
    }
    // ---- persistent per-lane state: c + input-side constants ----
    float creg[2][4];
#pragma unroll
    for (int ar = 0; ar < 2; ++ar)
#pragma unroll
        for (int r = 0; r < 4; ++r)
            creg[ar][r] = c0[(size_t)(rowbase + ar * 16 + lk * 4 + r) * HDIM + j];
    float wx0[4], wx1[4], bsum[4];
#pragma unroll
    for (int g = 0; g < 4; ++g) {
        int gr = g * HDIM + j;
        wx0[g]  = Wih[gr * 2];
        wx1[g]  = Wih[gr * 2 + 1];
        bsum[g] = bih[gr] + bhh[gr];
    }
    const float fcwj = fcw[j];

    grid.sync();

    for (int t = 0; t < TSTEPS; ++t) {
        const u16* __restrict__ hin = (t & 1) ? hb1 : hb0;
        u16* hout = (t & 1) ? hb0 : hb1;

        f32x4 acc[2][4];
#pragma unroll
        for (int a = 0; a < 2; ++a)
#pragma unroll
            for (int g = 0; g < 4; ++g)
                acc[a][g] = (f32x4){0.f, 0.f, 0.f, 0.f};

        const u16* arow = hin + (size_t)(rowbase + lr) * HDIM + lk * 8;

#pragma unroll 4
        for (int kc = 0; kc < 32; ++kc) {
            bf16x8 a0 = *(const bf16x8*)(arow + kc * 32);
            bf16x8 a1 = *(const bf16x8*)(arow + 16 * HDIM + kc * 32);
#pragma unroll
            for (int g = 0; g < 4; ++g) {
                int bc = g * 16 + lr;
                uint4 braw = wlds[bc][(kc * 4 + lk) ^ (bc & 7)];
                bf16x8 bfr = __builtin_bit_cast(bf16x8, braw);
                acc[0][g] = __builtin_amdgcn_mfma_f32_16x16x32_bf16(a0, bfr, acc[0][g], 0, 0, 0);
                acc[1][g] = __builtin_amdgcn_mfma_f32_16x16x32_bf16(a1, bfr, acc[1][g], 0, 0, 0);
            }
        }

        // Epilogue: lane-local cell update (all 4 gates at same (n, j) per lane)
#pragma unroll
        for (int ar = 0; ar < 2; ++ar)
#pragma unroll
            for (int r = 0; r < 4; ++r) {
                int n = rowbase + ar * 16 + lk * 4 + r;
                float prev = (t == 0) ? 0.f
                    : __hip_atomic_load(&out[n * TSTEPS + t - 1], __ATOMIC_RELAXED,
                                        __HIP_MEMORY_SCOPE_AGENT);
                float fdv = fd[n * TSTEPS + t];
                float gi = acc[ar][0][r] + wx0[0] * prev + wx1[0] * fdv + bsum[0];
                float gf = acc[ar][1][r] + wx0[1] * prev + wx1[1] * fdv + bsum[1];
                float gg = acc[ar][2][r] + wx0[2] * prev + wx1[2] * fdv + bsum[2];
                float go = acc[ar][3][r] + wx0[3] * prev + wx1[3] * fdv + bsum[3];
                float cn = sigf(gf) * creg[ar][r] + sigf(gi) * tanhfast(gg);
                creg[ar][r] = cn;
                float hn = sigf(go) * tanhfast(cn);
                hout[(size_t)n * HDIM + j] = (u16)f2bf(hn);
                float pr = fcwj * hn;
                pr += __shfl_xor(pr, 1);
                pr += __shfl_xor(pr, 2);
                pr += __shfl_xor(pr, 4);
                pr += __shfl_xor(pr, 8);
                if (lr == 0) atomicAdd(&out[n * TSTEPS + t], pr);
            }

        __threadfence();
        grid.sync();
    }
}

extern "C" void kernel_launch(void* const* d_in, const int* in_sizes, int n_in,
                              void* d_out, int out_size, void* d_ws, size_t ws_size,
                              hipStream_t stream) {
    const float* fd  = (const float*)d_in[0];
    const float* h0  = (const float*)d_in[1];
    const float* c0  = (const float*)d_in[2];
    const float* Wih = (const float*)d_in[3];
    const float* Whh = (const float*)d_in[4];
    const float* bih = (const float*)d_in[5];
    const float* bhh = (const float*)d_in[6];
    const float* fcw = (const float*)d_in[7];
    const float* fcb = (const float*)d_in[8];
    float* out = (float*)d_out;

    char* ws = (char*)d_ws;
    u16* hb0 = (u16*)(ws);
    u16* hb1 = (u16*)(ws + 4194304);

    void* kargs[] = { (void*)&fd, (void*)&h0, (void*)&c0, (void*)&Wih, (void*)&Whh,
                      (void*)&bih, (void*)&bhh, (void*)&fcw, (void*)&fcb,
                      (void*)&hb0, (void*)&hb1, (void*)&out };
    hipLaunchCooperativeKernel((const void*)k_persist, dim3(256), dim3(1024),
                               kargs, 0, stream);
}

// Round 3
// 1880.589 us; speedup vs baseline: 2.6525x; 2.6525x over previous
//
#include <hip/hip_runtime.h>
#include <hip/hip_bf16.h>

#define TSTEPS 32
#define HDIM 1024

typedef __bf16 bf16x8 __attribute__((ext_vector_type(8)));
typedef float f32x4 __attribute__((ext_vector_type(4)));
typedef unsigned short u16;
typedef unsigned int u32;

__device__ __forceinline__ u32 f2bf(float f) {
    u32 u = __float_as_uint(f);
    return (u + 0x7FFFu + ((u >> 16) & 1u)) >> 16;   // RNE
}
__device__ __forceinline__ u32 pack2(float a, float b) {
    return f2bf(a) | (f2bf(b) << 16);
}
__device__ __forceinline__ float sigf(float x) { return 1.f / (1.f + __expf(-x)); }
__device__ __forceinline__ float tanhfast(float x) { return 1.f - 2.f / (1.f + __expf(2.f * x)); }

// ws layout: Wp (8MB) @0 | hb0 (4MB) @8M | hb1 (4MB) @12M | cbuf (8MB) @16M

// Permuted bf16 W so that linear global_load_lds staging yields the
// XOR-swizzled LDS image directly (rule: linear LDS dest + inverse-swz source).
// Wp[(colT*16 + c)*1024 + bc*8 + u] = W8[jg(colT,bc)][c*8 + (u ^ (bc&7))]
//   bc in [0,128): gate = bc>>5, jl = bc&31;  jg = gate*1024 + colT*32 + jl
__global__ void k_prep_w(const float* __restrict__ W, uint4* __restrict__ Wp) {
    int o = blockIdx.x * 256 + threadIdx.x;          // 524288 16B units
    int colT = o >> 14, c = (o >> 10) & 15, l = o & 1023;
    int bc = l >> 3, u = l & 7;
    int jg = ((bc >> 5) << 10) + colT * 32 + (bc & 31);
    int kk = c * 64 + ((u ^ (bc & 7)) << 3);
    const float4* src = (const float4*)(W + (size_t)jg * HDIM + kk);
    float4 lo = src[0], hi = src[1];
    uint4 pk = { pack2(lo.x, lo.y), pack2(lo.z, lo.w), pack2(hi.x, hi.y), pack2(hi.z, hi.w) };
    Wp[o] = pk;
}

__global__ void k_prep_state(const float* __restrict__ h0, const float* __restrict__ c0,
                             u16* __restrict__ hb, float* __restrict__ c) {
    int i = blockIdx.x * 256 + threadIdx.x;          // x4 elems
    float4 v = ((const float4*)h0)[i];
    ushort4 o = { (u16)f2bf(v.x), (u16)f2bf(v.y), (u16)f2bf(v.z), (u16)f2bf(v.w) };
    ((ushort4*)hb)[i] = o;
    ((float4*)c)[i] = ((const float4*)c0)[i];
}

__global__ void k_init_out(float* __restrict__ out, const float* __restrict__ fcb) {
    int i = blockIdx.x * 256 + threadIdx.x;
    out[i] = fcb[0];
}

__device__ __forceinline__ void stage_chunk(const uint4* __restrict__ Wp, uint4* dst,
                                            int base_units, int tid) {
    // 1024 units (16KB): each thread 2 x global_load_lds width 16.
    // LDS dest is wave-uniform base; HW adds lane*16.
    const uint4* g0 = Wp + base_units + tid;
    uint4* l0 = dst + (tid & ~63);
    __builtin_amdgcn_global_load_lds((const __attribute__((address_space(1))) void*)g0,
                                     (__attribute__((address_space(3))) void*)l0, 16, 0, 0);
    __builtin_amdgcn_global_load_lds((const __attribute__((address_space(1))) void*)(g0 + 512),
                                     (__attribute__((address_space(3))) void*)(l0 + 512), 16, 0, 0);
}

// grid (32 colT, 16 rowT) x 512 thr (8 waves = 4 row x 2 col). 2 blocks/CU.
// Block: 128 rows x 128 gate-cols (32 j x 4 gates). Wave: 32 rows x 64 gc.
// Lane epilogue: all 4 gates for its (n, j) are lane-local.
__global__ __launch_bounds__(512, 4) void k_step(
    const u16* __restrict__ hin, u16* __restrict__ hout,
    float* __restrict__ c, const uint4* __restrict__ Wp,
    const float* __restrict__ fd, const float* __restrict__ Wih,
    const float* __restrict__ bih, const float* __restrict__ bhh,
    const float* __restrict__ fcw, float* out, int t)
{
    __shared__ uint4 lbuf[2][1024];                  // 32 KB double-buffer

    const int tid  = threadIdx.x;
    const int lane = tid & 63;
    const int wave = tid >> 6;
    const int lr = lane & 15, lk = lane >> 4;
    const int wc = wave & 1, wr = wave >> 1;
    const int colT = blockIdx.x;
    const int rowT = blockIdx.y;
    const int cb0  = colT * 16 * 1024;               // W chunk units base

    const u16* arow = hin + (size_t)(rowT * 128 + wr * 32 + lr) * HDIM + lk * 8;

    f32x4 acc[2][4];
#pragma unroll
    for (int a = 0; a < 2; ++a)
#pragma unroll
        for (int g = 0; g < 4; ++g)
            acc[a][g] = (f32x4){0.f, 0.f, 0.f, 0.f};

    stage_chunk(Wp, &lbuf[0][0], cb0, tid);
    __syncthreads();                                  // drains vmcnt before barrier

    for (int ch = 0; ch < 16; ++ch) {
        if (ch < 15)
            stage_chunk(Wp, &lbuf[(ch + 1) & 1][0], cb0 + (ch + 1) * 1024, tid);
        const uint4* buf = &lbuf[ch & 1][0];
#pragma unroll
        for (int kcl = 0; kcl < 2; ++kcl) {
            const int kg = ch * 2 + kcl;
            bf16x8 a0 = *(const bf16x8*)(arow + kg * 32);
            bf16x8 a1 = *(const bf16x8*)(arow + 16 * HDIM + kg * 32);
#pragma unroll
            for (int cf = 0; cf < 4; ++cf) {
                const int bc = cf * 32 + wc * 16 + lr;
                uint4 braw = buf[bc * 8 + ((kcl * 4 + lk) ^ (bc & 7))];
                bf16x8 bfr = __builtin_bit_cast(bf16x8, braw);
                acc[0][cf] = __builtin_amdgcn_mfma_f32_16x16x32_bf16(a0, bfr, acc[0][cf], 0, 0, 0);
                acc[1][cf] = __builtin_amdgcn_mfma_f32_16x16x32_bf16(a1, bfr, acc[1][cf], 0, 0, 0);
            }
        }
        __syncthreads();
    }

    // Epilogue: lane-local cell update, gate g in acc[ar][g][r] for this lane's j
    const int j = colT * 32 + wc * 16 + lr;
    float wx0[4], wx1[4], bs[4];
#pragma unroll
    for (int g = 0; g < 4; ++g) {
        int gr = g * HDIM + j;
        wx0[g] = Wih[2 * gr];
        wx1[g] = Wih[2 * gr + 1];
        bs[g]  = bih[gr] + bhh[gr];
    }
    const float fcwj = fcw[j];

#pragma unroll
    for (int ar = 0; ar < 2; ++ar)
#pragma unroll
        for (int r = 0; r < 4; ++r) {
            const int n = rowT * 128 + wr * 32 + ar * 16 + lk * 4 + r;
            float prev = (t == 0) ? 0.f : out[n * TSTEPS + t - 1];
            float fdv  = fd[n * TSTEPS + t];
            float gi = acc[ar][0][r] + wx0[0] * prev + wx1[0] * fdv + bs[0];
            float gf = acc[ar][1][r] + wx0[1] * prev + wx1[1] * fdv + bs[1];
            float gg = acc[ar][2][r] + wx0[2] * prev + wx1[2] * fdv + bs[2];
            float go = acc[ar][3][r] + wx0[3] * prev + wx1[3] * fdv + bs[3];
            float cold = c[(size_t)n * HDIM + j];
            float cn = sigf(gf) * cold + sigf(gi) * tanhfast(gg);
            c[(size_t)n * HDIM + j] = cn;
            float hn = sigf(go) * tanhfast(cn);
            hout[(size_t)n * HDIM + j] = (u16)f2bf(hn);
            float pr = fcwj * hn;
            pr += __shfl_xor(pr, 1);
            pr += __shfl_xor(pr, 2);
            pr += __shfl_xor(pr, 4);
            pr += __shfl_xor(pr, 8);
            if (lr == 0) atomicAdd(&out[n * TSTEPS + t], pr);
        }
}

extern "C" void kernel_launch(void* const* d_in, const int* in_sizes, int n_in,
                              void* d_out, int out_size, void* d_ws, size_t ws_size,
                              hipStream_t stream) {
    const float* fd  = (const float*)d_in[0];
    const float* h0  = (const float*)d_in[1];
    const float* c0  = (const float*)d_in[2];
    const float* Wih = (const float*)d_in[3];
    const float* Whh = (const float*)d_in[4];
    const float* bih = (const float*)d_in[5];
    const float* bhh = (const float*)d_in[6];
    const float* fcw = (const float*)d_in[7];
    const float* fcb = (const float*)d_in[8];
    float* out = (float*)d_out;

    char* ws = (char*)d_ws;
    uint4* Wp   = (uint4*)(ws);
    u16*   hb0  = (u16*)(ws + 8388608);
    u16*   hb1  = (u16*)(ws + 12582912);
    float* cbuf = (float*)(ws + 16777216);

    k_prep_w    <<<dim3(2048), dim3(256), 0, stream>>>(Whh, Wp);
    k_prep_state<<<dim3(2048), dim3(256), 0, stream>>>(h0, c0, hb0, cbuf);
    k_init_out  <<<dim3(256),  dim3(256), 0, stream>>>(out, fcb);

    for (int t = 0; t < TSTEPS; ++t) {
        const u16* hi = (t & 1) ? hb1 : hb0;
        u16*       ho = (t & 1) ? hb0 : hb1;
        k_step<<<dim3(32, 16), dim3(512), 0, stream>>>(hi, ho, cbuf, Wp, fd,
                                                        Wih, bih, bhh, fcw, out, t);
    }
}

// Round 4
// 1779.366 us; speedup vs baseline: 2.8034x; 1.0569x over previous
//
#include <hip/hip_runtime.h>
#include <hip/hip_bf16.h>

#define TSTEPS 32
#define HDIM 1024

typedef __bf16 bf16x8 __attribute__((ext_vector_type(8)));
typedef float f32x4 __attribute__((ext_vector_type(4)));
typedef unsigned short u16;
typedef unsigned int u32;

__device__ __forceinline__ u32 f2bf(float f) {
    u32 u = __float_as_uint(f);
    return (u + 0x7FFFu + ((u >> 16) & 1u)) >> 16;   // RNE
}
__device__ __forceinline__ u32 pack2(float a, float b) {
    return f2bf(a) | (f2bf(b) << 16);
}
__device__ __forceinline__ float sigf(float x) { return 1.f / (1.f + __expf(-x)); }
__device__ __forceinline__ float tanhfast(float x) { return 1.f - 2.f / (1.f + __expf(2.f * x)); }

// ws layout: Wp (8MB) @0 | hb0 (4MB) @8M | hb1 (4MB) @12M | cbuf (8MB) @16M

// Permuted bf16 W so linear global_load_lds staging yields the XOR-swizzled
// LDS image (linear LDS dest + inverse-swz source).
// Wp[(colT*16 + c)*1024 + bc*8 + u] = W8[jg(colT,bc)][c*8 + (u ^ (bc&7))]
//   bc in [0,128): gate = bc>>5, jl = bc&31;  jg = gate*1024 + colT*32 + jl
__global__ void k_prep_w(const float* __restrict__ W, uint4* __restrict__ Wp) {
    int o = blockIdx.x * 256 + threadIdx.x;          // 524288 16B units
    int colT = o >> 14, c = (o >> 10) & 15, l = o & 1023;
    int bc = l >> 3, u = l & 7;
    int jg = ((bc >> 5) << 10) + colT * 32 + (bc & 31);
    int kk = c * 64 + ((u ^ (bc & 7)) << 3);
    const float4* src = (const float4*)(W + (size_t)jg * HDIM + kk);
    float4 lo = src[0], hi = src[1];
    uint4 pk = { pack2(lo.x, lo.y), pack2(lo.z, lo.w), pack2(hi.x, hi.y), pack2(hi.z, hi.w) };
    Wp[o] = pk;
}

__global__ void k_prep_state(const float* __restrict__ h0, const float* __restrict__ c0,
                             u16* __restrict__ hb, float* __restrict__ c) {
    int i = blockIdx.x * 256 + threadIdx.x;          // x4 elems
    float4 v = ((const float4*)h0)[i];
    ushort4 o = { (u16)f2bf(v.x), (u16)f2bf(v.y), (u16)f2bf(v.z), (u16)f2bf(v.w) };
    ((ushort4*)hb)[i] = o;
    ((float4*)c)[i] = ((const float4*)c0)[i];
}

__global__ void k_init_out(float* __restrict__ out, const float* __restrict__ fcb) {
    int i = blockIdx.x * 256 + threadIdx.x;
    out[i] = fcb[0];
}

__device__ __forceinline__ void stage_chunk(const uint4* __restrict__ g, uint4* dst, int tid) {
    // 2048 units (32KB): each thread 4 x global_load_lds width 16.
    const uint4* g0 = g + tid;
    uint4* l0 = dst + (tid & ~63);
#pragma unroll
    for (int i = 0; i < 4; ++i)
        __builtin_amdgcn_global_load_lds(
            (const __attribute__((address_space(1))) void*)(g0 + i * 512),
            (__attribute__((address_space(3))) void*)(l0 + i * 512), 16, 0, 0);
}

// grid (16 rowT, 32 colT) x 512 thr (8 waves = 4 row x 2 col). 2 blocks/CU.
// blockIdx.x = rowT so XCD = blkid%8 = rowT%8: all 32 colT blocks sharing a
// 128-row h/c/out panel live on one XCD -> h,c,prev,fd reads are local-L2 hits.
// Block: 128 rows x 128 gate-cols (32 j x 4 gates). Lane holds all 4 gates of
// its (n, j) -> cell update is lane-local.
__global__ __launch_bounds__(512, 4) void k_step(
    const u16* __restrict__ hin, u16* __restrict__ hout,
    float* __restrict__ c, const uint4* __restrict__ Wp,
    const float* __restrict__ fd, const float* __restrict__ Wih,
    const float* __restrict__ bih, const float* __restrict__ bhh,
    const float* __restrict__ fcw, float* out, int t)
{
    __shared__ uint4 lbuf[2][2048];                  // 64 KB double-buffer

    const int tid  = threadIdx.x;
    const int lane = tid & 63;
    const int wave = tid >> 6;
    const int lr = lane & 15, lk = lane >> 4;
    const int wc = wave & 1, wr = wave >> 1;
    const int rowT = blockIdx.x;                     // XCD = rowT % 8
    const int colT = blockIdx.y;
    const uint4* wbase = Wp + colT * 16384;          // 16K units per colT

    const u16* arow = hin + (size_t)(rowT * 128 + wr * 32 + lr) * HDIM + lk * 8;

    f32x4 acc[2][4];
#pragma unroll
    for (int a = 0; a < 2; ++a)
#pragma unroll
        for (int g = 0; g < 4; ++g)
            acc[a][g] = (f32x4){0.f, 0.f, 0.f, 0.f};

    // A double-buffer in registers: chunk ch+1 loads issue BEFORE the barrier
    // so their latency hides under chunk ch's MFMAs (full unroll -> static idx).
    bf16x8 A0[2][4], A1[2][4];
#pragma unroll
    for (int kcl = 0; kcl < 4; ++kcl) {
        A0[0][kcl] = *(const bf16x8*)(arow + kcl * 32);
        A1[0][kcl] = *(const bf16x8*)(arow + 16 * HDIM + kcl * 32);
    }
    stage_chunk(wbase, &lbuf[0][0], tid);
    __syncthreads();

#pragma unroll
    for (int ch = 0; ch < 8; ++ch) {
        if (ch < 7) {
            stage_chunk(wbase + (ch + 1) * 2048, &lbuf[(ch + 1) & 1][0], tid);
#pragma unroll
            for (int kcl = 0; kcl < 4; ++kcl) {
                const int kg = (ch + 1) * 4 + kcl;
                A0[(ch + 1) & 1][kcl] = *(const bf16x8*)(arow + kg * 32);
                A1[(ch + 1) & 1][kcl] = *(const bf16x8*)(arow + 16 * HDIM + kg * 32);
            }
        }
        const uint4* buf = &lbuf[ch & 1][0];
#pragma unroll
        for (int kcl = 0; kcl < 4; ++kcl) {
            bf16x8 a0 = A0[ch & 1][kcl];
            bf16x8 a1 = A1[ch & 1][kcl];
#pragma unroll
            for (int cf = 0; cf < 4; ++cf) {
                const int bc = cf * 32 + wc * 16 + lr;
                uint4 braw = buf[(kcl >> 1) * 1024 + bc * 8 +
                                 ((((kcl & 1) << 2) + lk) ^ (bc & 7))];
                bf16x8 bfr = __builtin_bit_cast(bf16x8, braw);
                acc[0][cf] = __builtin_amdgcn_mfma_f32_16x16x32_bf16(a0, bfr, acc[0][cf], 0, 0, 0);
                acc[1][cf] = __builtin_amdgcn_mfma_f32_16x16x32_bf16(a1, bfr, acc[1][cf], 0, 0, 0);
            }
        }
        __syncthreads();
    }

    // Epilogue: lane-local cell update, gate g in acc[ar][g][r] for this lane's j
    const int j = colT * 32 + wc * 16 + lr;
    float wx0[4], wx1[4], bs[4];
#pragma unroll
    for (int g = 0; g < 4; ++g) {
        int gr = g * HDIM + j;
        wx0[g] = Wih[2 * gr];
        wx1[g] = Wih[2 * gr + 1];
        bs[g]  = bih[gr] + bhh[gr];
    }
    const float fcwj = fcw[j];

#pragma unroll
    for (int ar = 0; ar < 2; ++ar)
#pragma unroll
        for (int r = 0; r < 4; ++r) {
            const int n = rowT * 128 + wr * 32 + ar * 16 + lk * 4 + r;
            float prev = (t == 0) ? 0.f : out[n * TSTEPS + t - 1];
            float fdv  = fd[n * TSTEPS + t];
            float gi = acc[ar][0][r] + wx0[0] * prev + wx1[0] * fdv + bs[0];
            float gf = acc[ar][1][r] + wx0[1] * prev + wx1[1] * fdv + bs[1];
            float gg = acc[ar][2][r] + wx0[2] * prev + wx1[2] * fdv + bs[2];
            float go = acc[ar][3][r] + wx0[3] * prev + wx1[3] * fdv + bs[3];
            float cold = c[(size_t)n * HDIM + j];
            float cn = sigf(gf) * cold + sigf(gi) * tanhfast(gg);
            c[(size_t)n * HDIM + j] = cn;
            float hn = sigf(go) * tanhfast(cn);
            hout[(size_t)n * HDIM + j] = (u16)f2bf(hn);
            float pr = fcwj * hn;
            pr += __shfl_xor(pr, 1);
            pr += __shfl_xor(pr, 2);
            pr += __shfl_xor(pr, 4);
            pr += __shfl_xor(pr, 8);
            if (lr == 0) atomicAdd(&out[n * TSTEPS + t], pr);
        }
}

extern "C" void kernel_launch(void* const* d_in, const int* in_sizes, int n_in,
                              void* d_out, int out_size, void* d_ws, size_t ws_size,
                              hipStream_t stream) {
    const float* fd  = (const float*)d_in[0];
    const float* h0  = (const float*)d_in[1];
    const float* c0  = (const float*)d_in[2];
    const float* Wih = (const float*)d_in[3];
    const float* Whh = (const float*)d_in[4];
    const float* bih = (const float*)d_in[5];
    const float* bhh = (const float*)d_in[6];
    const float* fcw = (const float*)d_in[7];
    const float* fcb = (const float*)d_in[8];
    float* out = (float*)d_out;

    char* ws = (char*)d_ws;
    uint4* Wp   = (uint4*)(ws);
    u16*   hb0  = (u16*)(ws + 8388608);
    u16*   hb1  = (u16*)(ws + 12582912);
    float* cbuf = (float*)(ws + 16777216);

    k_prep_w    <<<dim3(2048), dim3(256), 0, stream>>>(Whh, Wp);
    k_prep_state<<<dim3(2048), dim3(256), 0, stream>>>(h0, c0, hb0, cbuf);
    k_init_out  <<<dim3(256),  dim3(256), 0, stream>>>(out, fcb);

    for (int t = 0; t < TSTEPS; ++t) {
        const u16* hi = (t & 1) ? hb1 : hb0;
        u16*       ho = (t & 1) ? hb0 : hb1;
        k_step<<<dim3(16, 32), dim3(512), 0, stream>>>(hi, ho, cbuf, Wp, fd,
                                                        Wih, bih, bhh, fcw, out, t);
    }
}